// Round 5
// baseline (128.512 us; speedup 1.0000x reference)
//
#include <hip/hip_runtime.h>
#include <math.h>

#define N_SQ   7          // 7 squarings -> A^128; Frobenius -> trace(A^256)
#define INV_P  (1.0f / 256.0f)
#define EPS_F  1e-20f
#define PH     72         // f16 pitch for staged 64-row planes
#define PQ     67         // f32 pitch for Q1 transpose buffer
#define PLANE  (64 * PH)  // f16 elements per plane

typedef _Float16 h2    __attribute__((ext_vector_type(2)));
typedef _Float16 f16x8 __attribute__((ext_vector_type(8)));
typedef float    f32x4 __attribute__((ext_vector_type(4)));

__device__ inline float cdot2(h2 a, h2 b, float c) {
#if __has_builtin(__builtin_amdgcn_fdot2)
    return __builtin_amdgcn_fdot2(a, b, c, false);
#else
    return c + (float)a.x * (float)b.x + (float)a.y * (float)b.y;
#endif
}
__device__ inline h2 bch2(unsigned int x) { return __builtin_bit_cast(h2, x); }
__device__ inline h2 bch2f(float x)       { return __builtin_bit_cast(h2, x); }
__device__ inline float bcf(h2 x)         { return __builtin_bit_cast(float, x); }

// ws: raw res_final per (b,s): ws[bs*512 + g], 72*512 floats; cnt: 8 ints after.

__global__ __launch_bounds__(512, 1) void ista_main_kernel(
    const float* __restrict__ Dre, const float* __restrict__ Dim,
    const float* __restrict__ Cre, const float* __restrict__ Cim,
    float* __restrict__ out, float* __restrict__ ws, int* __restrict__ cnt)
{
    const int bs = blockIdx.x;     // 0..71
    const int t  = threadIdx.x;    // 0..511
    const int wv = t >> 6;         // wave 0..7
    const int ln = t & 63;         // lane
    const int c16 = ln & 15;       // MFMA col / row-select
    const int qd  = ln >> 4;       // MFMA quad
    const float* __restrict__ dre = Dre + (size_t)bs * 32768;
    const float* __restrict__ dim = Dim + (size_t)bs * 32768;

    // uBuf floats[12800]:
    //   [0,2304)     ShRe f16[PLANE]
    //   [2304,4608)  ShIm f16[PLANE]
    //   [4608,8896)  Q1 f32[64*PQ]           (dead after last epilogue)
    //   [4608,12800) resHist f32[16*512]     (Phase E+, aliases Q1)
    // Phase E aliases (planes dead): sUp ping-pong [0,2048),
    //   sResH f16 @ floats [2048,2304), sHuMe @ [2304,3328)
    __shared__ __align__(16) float uBuf[12800];         // 51200 B
    _Float16* ShRe  = (_Float16*)uBuf;
    _Float16* ShIm  = (_Float16*)uBuf + PLANE;
    float*    Q1    = uBuf + 4608;
    float*    resHist = uBuf + 4608;
    _Float16* sResH = (_Float16*)(uBuf + 2048);
    __shared__ __align__(16) float s_r[128];
    __shared__ float s_red[32];
    __shared__ int s_flag;

    // ---------------- Phase A: r = vec(C^T) ----------------
    // (visibility covered by Phase C's first barrier; s_r read only in Phase B)
    if (t < 64) {
        int i = t >> 3, j = t & 7;
        s_r[2 * t]     = Cre[bs * 64 + j * 8 + i];
        s_r[2 * t + 1] = Cim[bs * 64 + j * 8 + i];
    }

    // ---------------- MFMA tile ownership ----------------
    const int tau0 = 2 * wv, tau1 = 2 * wv + 1;
    const int I0 = tau0 >> 2, J0 = tau0 & 3;
    const int I1 = tau1 >> 2, J1 = tau1 & 3;

    // per-thread redundant scalars (bit-identical across threads)
    float Elog = 0.f, gamma = 0.f;

    auto epilogue = [&](f32x4 P0, f32x4 Qa0, f32x4 P1, f32x4 Qa1, bool first, bool last) {
        #pragma unroll
        for (int r = 0; r < 4; ++r) {
            Q1[(I0 * 16 + qd * 4 + r) * PQ + J0 * 16 + c16] = Qa0[r];
            Q1[(I1 * 16 + qd * 4 + r) * PQ + J1 * 16 + c16] = Qa1[r];
        }
        float dv = 0.f;
        if (I0 == J0) {
            #pragma unroll
            for (int r = 0; r < 4; ++r) if (qd * 4 + r == c16) dv = fmaxf(dv, fabsf(P0[r]));
        }
        if (I1 == J1) {
            #pragma unroll
            for (int r = 0; r < 4; ++r) if (qd * 4 + r == c16) dv = fmaxf(dv, fabsf(P1[r]));
        }
        for (int off = 32; off; off >>= 1) dv = fmaxf(dv, __shfl_down(dv, off, 64));
        if (ln == 0) s_red[wv] = dv;
        __syncthreads();                         // covers Q1 writes + s_red
        float m = s_red[0];
        #pragma unroll
        for (int k = 1; k < 8; ++k) m = fmaxf(m, s_red[k]);
        Elog = first ? log2f(m) : 2.f * Elog + log2f(m);
        float ic = 1.f / m;
        float ci0[4], ci1[4];
        #pragma unroll
        for (int r = 0; r < 4; ++r) {
            ci0[r] = Qa0[r] - Q1[(J0 * 16 + c16) * PQ + I0 * 16 + qd * 4 + r];
            ci1[r] = Qa1[r] - Q1[(J1 * 16 + c16) * PQ + I1 * 16 + qd * 4 + r];
        }
        if (!last) {
            #pragma unroll
            for (int r = 0; r < 4; ++r) {
                ShRe[(I0 * 16 + qd * 4 + r) * PH + J0 * 16 + c16] = (_Float16)(P0[r] * ic);
                ShIm[(I0 * 16 + qd * 4 + r) * PH + J0 * 16 + c16] = (_Float16)(ci0[r] * ic);
                ShRe[(I1 * 16 + qd * 4 + r) * PH + J1 * 16 + c16] = (_Float16)(P1[r] * ic);
                ShIm[(I1 * 16 + qd * 4 + r) * PH + J1 * 16 + c16] = (_Float16)(ci1[r] * ic);
            }
            __syncthreads();
        } else {
            float fr = 0.f;
            #pragma unroll
            for (int r = 0; r < 4; ++r)
                fr += P0[r] * P0[r] + ci0[r] * ci0[r] + P1[r] * P1[r] + ci1[r] * ci1[r];
            fr *= ic * ic;
            for (int off = 32; off; off >>= 1) fr += __shfl_down(fr, off, 64);
            if (ln == 0) s_red[8 + wv] = fr;     // disjoint from s_red[0..8) read above
            __syncthreads();
            float fsum = 0.f;
            #pragma unroll
            for (int k = 0; k < 8; ++k) fsum += s_red[8 + k];
            gamma = exp2f(-(2.f * Elog + log2f(fsum)) * INV_P);
            // no guard barrier: Phase B uses disjoint s_red[16..32)
        }
    };

    // ---------------- Phase C: Gram via MFMA (single-buffer, 2 barriers/chunk) ----------
    h2 du_re[32], du_im[32];   // g-pairs of row ln, g in [64wv, 64wv+64)
    f32x4 gP0 = {0.f, 0.f, 0.f, 0.f}, gQ0 = {0.f, 0.f, 0.f, 0.f};
    f32x4 gP1 = {0.f, 0.f, 0.f, 0.f}, gQ1 = {0.f, 0.f, 0.f, 0.f};
    {
        const int srow = t >> 4;          // 0..31
        const int scb  = (t & 15) * 4;    // col base in chunk
        float4 pr0, pi0, pr1, pi1;
        pr0 = *(const float4*)&dre[srow * 512 + scb];
        pi0 = *(const float4*)&dim[srow * 512 + scb];
        pr1 = *(const float4*)&dre[(srow + 32) * 512 + scb];
        pi1 = *(const float4*)&dim[(srow + 32) * 512 + scb];
        for (int ch = 0; ch < 8; ++ch) {
            *(h2*)&ShRe[srow * PH + scb]     = h2{(_Float16)pr0.x, (_Float16)pr0.y};
            *(h2*)&ShRe[srow * PH + scb + 2] = h2{(_Float16)pr0.z, (_Float16)pr0.w};
            *(h2*)&ShIm[srow * PH + scb]     = h2{(_Float16)pi0.x, (_Float16)pi0.y};
            *(h2*)&ShIm[srow * PH + scb + 2] = h2{(_Float16)pi0.z, (_Float16)pi0.w};
            *(h2*)&ShRe[(srow + 32) * PH + scb]     = h2{(_Float16)pr1.x, (_Float16)pr1.y};
            *(h2*)&ShRe[(srow + 32) * PH + scb + 2] = h2{(_Float16)pr1.z, (_Float16)pr1.w};
            *(h2*)&ShIm[(srow + 32) * PH + scb]     = h2{(_Float16)pi1.x, (_Float16)pi1.y};
            *(h2*)&ShIm[(srow + 32) * PH + scb + 2] = h2{(_Float16)pi1.z, (_Float16)pi1.w};
            if (ch < 7) {   // register prefetch: no LDS/store in flight -> no barrier drain
                int gc = (ch + 1) * 64;
                pr0 = *(const float4*)&dre[srow * 512 + gc + scb];
                pi0 = *(const float4*)&dim[srow * 512 + gc + scb];
                pr1 = *(const float4*)&dre[(srow + 32) * 512 + gc + scb];
                pi1 = *(const float4*)&dim[(srow + 32) * 512 + gc + scb];
            }
            __syncthreads();
            #pragma unroll
            for (int ks = 0; ks < 64; ks += 32) {
                f16x8 arI0 = *(const f16x8*)&ShRe[(I0 * 16 + c16) * PH + ks + qd * 8];
                f16x8 aiI0 = *(const f16x8*)&ShIm[(I0 * 16 + c16) * PH + ks + qd * 8];
                f16x8 arJ0 = *(const f16x8*)&ShRe[(J0 * 16 + c16) * PH + ks + qd * 8];
                f16x8 aiJ0 = *(const f16x8*)&ShIm[(J0 * 16 + c16) * PH + ks + qd * 8];
                gP0 = __builtin_amdgcn_mfma_f32_16x16x32_f16(arI0, arJ0, gP0, 0, 0, 0);
                gP0 = __builtin_amdgcn_mfma_f32_16x16x32_f16(aiI0, aiJ0, gP0, 0, 0, 0);
                gQ0 = __builtin_amdgcn_mfma_f32_16x16x32_f16(aiI0, arJ0, gQ0, 0, 0, 0);
                f16x8 arI1 = *(const f16x8*)&ShRe[(I1 * 16 + c16) * PH + ks + qd * 8];
                f16x8 aiI1 = *(const f16x8*)&ShIm[(I1 * 16 + c16) * PH + ks + qd * 8];
                f16x8 arJ1 = *(const f16x8*)&ShRe[(J1 * 16 + c16) * PH + ks + qd * 8];
                f16x8 aiJ1 = *(const f16x8*)&ShIm[(J1 * 16 + c16) * PH + ks + qd * 8];
                gP1 = __builtin_amdgcn_mfma_f32_16x16x32_f16(arI1, arJ1, gP1, 0, 0, 0);
                gP1 = __builtin_amdgcn_mfma_f32_16x16x32_f16(aiI1, aiJ1, gP1, 0, 0, 0);
                gQ1 = __builtin_amdgcn_mfma_f32_16x16x32_f16(aiI1, arJ1, gQ1, 0, 0, 0);
            }
            if (ch == wv) {
                #pragma unroll
                for (int c = 0; c < 8; ++c) {
                    uint4 aw = *(const uint4*)&ShRe[ln * PH + 8 * c];
                    du_re[4 * c + 0] = bch2(aw.x); du_re[4 * c + 1] = bch2(aw.y);
                    du_re[4 * c + 2] = bch2(aw.z); du_re[4 * c + 3] = bch2(aw.w);
                    uint4 bw = *(const uint4*)&ShIm[ln * PH + 8 * c];
                    du_im[4 * c + 0] = bch2(bw.x); du_im[4 * c + 1] = bch2(bw.y);
                    du_im[4 * c + 2] = bch2(bw.z); du_im[4 * c + 3] = bch2(bw.w);
                }
            }
            __syncthreads();
        }
    }
    epilogue(gP0, gQ0, gP1, gQ1, true, false);

    // ---------------- Phase D: 7 scaled squarings via MFMA ----------------
    for (int sq = 0; sq < N_SQ; ++sq) {
        f32x4 P0 = {0.f, 0.f, 0.f, 0.f}, Qa0 = {0.f, 0.f, 0.f, 0.f};
        f32x4 P1 = {0.f, 0.f, 0.f, 0.f}, Qa1 = {0.f, 0.f, 0.f, 0.f};
        #pragma unroll
        for (int ks = 0; ks < 64; ks += 32) {
            f16x8 arI0 = *(const f16x8*)&ShRe[(I0 * 16 + c16) * PH + ks + qd * 8];
            f16x8 aiI0 = *(const f16x8*)&ShIm[(I0 * 16 + c16) * PH + ks + qd * 8];
            f16x8 arJ0 = *(const f16x8*)&ShRe[(J0 * 16 + c16) * PH + ks + qd * 8];
            f16x8 aiJ0 = *(const f16x8*)&ShIm[(J0 * 16 + c16) * PH + ks + qd * 8];
            P0  = __builtin_amdgcn_mfma_f32_16x16x32_f16(arI0, arJ0, P0, 0, 0, 0);
            P0  = __builtin_amdgcn_mfma_f32_16x16x32_f16(aiI0, aiJ0, P0, 0, 0, 0);
            Qa0 = __builtin_amdgcn_mfma_f32_16x16x32_f16(aiI0, arJ0, Qa0, 0, 0, 0);
            f16x8 arI1 = *(const f16x8*)&ShRe[(I1 * 16 + c16) * PH + ks + qd * 8];
            f16x8 aiI1 = *(const f16x8*)&ShIm[(I1 * 16 + c16) * PH + ks + qd * 8];
            f16x8 arJ1 = *(const f16x8*)&ShRe[(J1 * 16 + c16) * PH + ks + qd * 8];
            f16x8 aiJ1 = *(const f16x8*)&ShIm[(J1 * 16 + c16) * PH + ks + qd * 8];
            P1  = __builtin_amdgcn_mfma_f32_16x16x32_f16(arI1, arJ1, P1, 0, 0, 0);
            P1  = __builtin_amdgcn_mfma_f32_16x16x32_f16(aiI1, aiJ1, P1, 0, 0, 0);
            Qa1 = __builtin_amdgcn_mfma_f32_16x16x32_f16(aiI1, arJ1, Qa1, 0, 0, 0);
        }
        epilogue(P0, Qa0, P1, Qa1, false, sq == N_SQ - 1);
    }

    // ---------------- Phase B (after D): Dhr[g] + dV column tile; L2-warm loads ----------
    float dhr_re, dhr_im, res_g, theta;
    h2 dV[64];    // D[m][t] packed (re,im) f16
    {
        float dr0 = 0.f, dr1 = 0.f, di0 = 0.f, di1 = 0.f;
        #pragma unroll
        for (int m = 0; m < 64; ++m) {
            float ar = dre[m * 512 + t], ai = dim[m * 512 + t];
            dV[m] = h2{(_Float16)ar, (_Float16)ai};
            float rr = s_r[2 * m], ri = s_r[2 * m + 1];
            if (m & 1) { dr1 += ar * rr + ai * ri; di1 += ar * ri - ai * rr; }
            else       { dr0 += ar * rr + ai * ri; di0 += ar * ri - ai * rr; }
        }
        dhr_re = dr0 + dr1; dhr_im = di0 + di1;
        float sv = dhr_re * dhr_re;
        float mv = sqrtf(dhr_re * dhr_re + dhr_im * dhr_im);
        for (int off = 32; off; off >>= 1) {
            sv += __shfl_down(sv, off, 64);
            mv = fmaxf(mv, __shfl_down(mv, off, 64));
        }
        if (ln == 0) { s_red[16 + wv] = sv; s_red[24 + wv] = mv; }   // disjoint slots
        __syncthreads();
        float ss = 0.f, mmx = 0.f;
        #pragma unroll
        for (int k = 0; k < 8; ++k) { ss += s_red[16 + k]; mmx = fmaxf(mmx, s_red[24 + k]); }
        res_g = dhr_re / (sqrtf(ss) + EPS_F);
        theta = 0.5f * mmx * gamma;
    }

    // ---------------- Phase E: 16 ISTA layers, 1 barrier/layer, no global stores --------
    const int resh_base = 64 * wv;
    float* const sHuMe = uBuf + 2304 + wv * 128;   // wave-private hu copy

    for (int l = 0; l < 16; ++l) {
        sResH[t] = (_Float16)res_g;          // wave-private range, read by own wave only
        float uA = 0.f, uB = 0.f, vA = 0.f, vB = 0.f;
        #pragma unroll
        for (int c = 0; c < 8; ++c) {
            uint4 rw = *(const uint4*)&sResH[resh_base + 8 * c];
            h2 r0 = bch2(rw.x), r1 = bch2(rw.y), r2 = bch2(rw.z), r3 = bch2(rw.w);
            uA = cdot2(du_re[4 * c + 0], r0, uA);  vA = cdot2(du_im[4 * c + 0], r0, vA);
            uB = cdot2(du_re[4 * c + 1], r1, uB);  vB = cdot2(du_im[4 * c + 1], r1, vB);
            uA = cdot2(du_re[4 * c + 2], r2, uA);  vA = cdot2(du_im[4 * c + 2], r2, vA);
            uB = cdot2(du_re[4 * c + 3], r3, uB);  vB = cdot2(du_im[4 * c + 3], r3, vB);
        }
        float* sUpL = uBuf + (l & 1) * 1024;   // ping-pong partial buffer
        *(float2*)&sUpL[t * 2] = make_float2(uA + uB, vA + vB);
        __syncthreads();                       // the only barrier this layer (LDS-only drain)
        // every wave redundantly reduces (bit-identical across waves)
        float uR = 0.f, uI = 0.f;
        #pragma unroll
        for (int w8 = 0; w8 < 8; ++w8) {
            float2 p = *(const float2*)&sUpL[(w8 * 64 + ln) * 2];
            uR += p.x; uI += p.y;
        }
        h2 hu1 = h2{(_Float16)uR, (_Float16)uI};
        h2 hu2 = h2{(_Float16)uI, (_Float16)(-uR)};
        *(float2*)&sHuMe[2 * ln] = make_float2(bcf(hu1), bcf(hu2));
        // in-wave readback of own sHu copy (ds in-order, no barrier)
        float wRa = 0.f, wRb = 0.f, wIa = 0.f, wIb = 0.f;
        #pragma unroll
        for (int mm = 0; mm < 32; ++mm) {
            float4 hq = *(const float4*)&sHuMe[4 * mm];
            wRa = cdot2(dV[2 * mm],     bch2f(hq.x), wRa);
            wIa = cdot2(dV[2 * mm],     bch2f(hq.y), wIa);
            wRb = cdot2(dV[2 * mm + 1], bch2f(hq.z), wRb);
            wIb = cdot2(dV[2 * mm + 1], bch2f(hq.w), wIb);
        }
        float sre = res_g + gamma * (dhr_re - (wRa + wRb));
        float sim = gamma * (dhr_im - (wIa + wIb));
        float mag = sqrtf(sre * sre + sim * sim);
        res_g = fmaxf(mag - theta, 0.f);
        resHist[l * 512 + t] = res_g;          // LDS, own slot, no drain at next barrier
    }

    // ---------------- Phase F: per-(b,s) minmax + raw store ----------------
    {
        float mn = res_g, mx = res_g;
        for (int off = 32; off; off >>= 1) {
            mn = fminf(mn, __shfl_down(mn, off, 64));
            mx = fmaxf(mx, __shfl_down(mx, off, 64));
        }
        if (ln == 0) { s_red[wv] = mn; s_red[8 + wv] = mx; }
        __syncthreads();
        float lo = s_red[0], hi = s_red[8];
        #pragma unroll
        for (int k = 1; k < 8; ++k) { lo = fminf(lo, s_red[k]); hi = fmaxf(hi, s_red[8 + k]); }
        out[bs * 512 + t] = (res_g - lo) / (hi - lo + EPS_F);
        ws[bs * 512 + t] = res_g;
    }

    // ---------------- bulk out_init store (deferred from Phase E) ----------------
    {
        float* out_init = out + 40960 + (size_t)bs * 8192;
        #pragma unroll
        for (int l = 0; l < 16; ++l)
            out_init[l * 512 + t] = resHist[l * 512 + t];   // own slot, no barrier needed
    }

    // ---------------- Phase G: fused ave (last block of each b) ----------------
    if (cnt != nullptr) {
        const int b = bs / 9;
        __threadfence();                       // release ws writes to device scope
        if (t == 0) s_flag = (atomicAdd(&cnt[b], 1) == 8);
        __syncthreads();                       // also separates Phase F s_red reads
        if (!s_flag) return;                   // block-uniform
        __threadfence();                       // acquire side
        float acc = 0.f;
        #pragma unroll
        for (int s = 0; s < 9; ++s) acc += ws[(b * 9 + s) * 512 + t];
        acc *= (1.f / 9.f);
        float mn = acc, mx = acc;
        for (int off = 32; off; off >>= 1) {
            mn = fminf(mn, __shfl_down(mn, off, 64));
            mx = fmaxf(mx, __shfl_down(mx, off, 64));
        }
        if (ln == 0) { s_red[wv] = mn; s_red[8 + wv] = mx; }
        __syncthreads();
        float lo = s_red[0], hi = s_red[8];
        #pragma unroll
        for (int k = 1; k < 8; ++k) { lo = fminf(lo, s_red[k]); hi = fmaxf(hi, s_red[8 + k]); }
        out[36864 + b * 512 + t] = (acc - lo) / (hi - lo + EPS_F);
    }
}

__global__ __launch_bounds__(512) void ista_ave_kernel(
    const float* __restrict__ ws, float* __restrict__ out)
{
    const int b = blockIdx.x;    // 0..7
    const int g = threadIdx.x;   // 0..511
    __shared__ float s_red[16];
    float acc = 0.f;
    #pragma unroll
    for (int s = 0; s < 9; ++s) acc += ws[(b * 9 + s) * 512 + g];
    acc *= (1.f / 9.f);
    float mn = acc, mx = acc;
    for (int off = 32; off; off >>= 1) {
        mn = fminf(mn, __shfl_down(mn, off, 64));
        mx = fmaxf(mx, __shfl_down(mx, off, 64));
    }
    if ((g & 63) == 0) { s_red[g >> 6] = mn; s_red[8 + (g >> 6)] = mx; }
    __syncthreads();
    float lo = s_red[0], hi = s_red[8];
    #pragma unroll
    for (int k = 1; k < 8; ++k) { lo = fminf(lo, s_red[k]); hi = fmaxf(hi, s_red[8 + k]); }
    out[36864 + b * 512 + g] = (acc - lo) / (hi - lo + EPS_F);
}

extern "C" void kernel_launch(void* const* d_in, const int* in_sizes, int n_in,
                              void* d_out, int out_size, void* d_ws, size_t ws_size,
                              hipStream_t stream) {
    const float* Dre = (const float*)d_in[0];
    const float* Dim = (const float*)d_in[1];
    const float* Cre = (const float*)d_in[2];
    const float* Cim = (const float*)d_in[3];
    float* out = (float*)d_out;
    float* ws  = (float*)d_ws;

    const size_t cnt_off = (size_t)36864 * 4;              // bytes: after ws res_final
    const bool fuse = ws_size >= cnt_off + 8 * sizeof(int);
    int* cnt = fuse ? (int*)((char*)d_ws + cnt_off) : nullptr;
    if (fuse) hipMemsetAsync(cnt, 0, 8 * sizeof(int), stream);

    ista_main_kernel<<<72, 512, 0, stream>>>(Dre, Dim, Cre, Cim, out, ws, cnt);
    if (!fuse) ista_ave_kernel<<<8, 512, 0, stream>>>(ws, out);
}

// Round 6
// 110.647 us; speedup vs baseline: 1.1615x; 1.1615x over previous
//
#include <hip/hip_runtime.h>
#include <math.h>

#define N_SQ   7          // 7 squarings -> A^128; Frobenius -> trace(A^256)
#define INV_P  (1.0f / 256.0f)
#define EPS_F  1e-20f
#define PH     72         // f16 pitch for staged 64-row planes
#define PQ     67         // f32 pitch for Q1 transpose buffer
#define PLANE  (64 * PH)  // f16 elements per plane

typedef _Float16 h2    __attribute__((ext_vector_type(2)));
typedef _Float16 f16x8 __attribute__((ext_vector_type(8)));
typedef float    f32x4 __attribute__((ext_vector_type(4)));

__device__ inline float cdot2(h2 a, h2 b, float c) {
#if __has_builtin(__builtin_amdgcn_fdot2)
    return __builtin_amdgcn_fdot2(a, b, c, false);
#else
    return c + (float)a.x * (float)b.x + (float)a.y * (float)b.y;
#endif
}
__device__ inline h2 bch2(unsigned int x) { return __builtin_bit_cast(h2, x); }
__device__ inline h2 bch2f(float x)       { return __builtin_bit_cast(h2, x); }
__device__ inline float bcf(h2 x)         { return __builtin_bit_cast(float, x); }

// ws: raw res_final per (b,s): ws[bs*512 + g], 72*512 floats.

__global__ __launch_bounds__(512, 1) void ista_main_kernel(
    const float* __restrict__ Dre, const float* __restrict__ Dim,
    const float* __restrict__ Cre, const float* __restrict__ Cim,
    float* __restrict__ out, float* __restrict__ ws)
{
    const int bs = blockIdx.x;     // 0..71
    const int t  = threadIdx.x;    // 0..511
    const int wv = t >> 6;         // wave 0..7
    const int ln = t & 63;         // lane
    const int c16 = ln & 15;       // MFMA col / row-select
    const int qd  = ln >> 4;       // MFMA quad
    const float* __restrict__ dre = Dre + (size_t)bs * 32768;
    const float* __restrict__ dim = Dim + (size_t)bs * 32768;

    // uBuf floats[12800]:
    //   [0,2304)     ShRe f16[PLANE]
    //   [2304,4608)  ShIm f16[PLANE]
    //   [4608,8896)  Q1 f32[64*PQ]           (dead after last epilogue)
    //   [4608,12800) resHist f32[16*512]     (Phase E+, aliases Q1)
    // Phase E aliases (planes dead): sUp ping-pong [0,2048),
    //   sResH f16 @ floats [2048,2304), sHuMe @ [2304,3328)
    __shared__ __align__(16) float uBuf[12800];         // 51200 B
    _Float16* ShRe  = (_Float16*)uBuf;
    _Float16* ShIm  = (_Float16*)uBuf + PLANE;
    float*    Q1    = uBuf + 4608;
    float*    resHist = uBuf + 4608;
    _Float16* sResH = (_Float16*)(uBuf + 2048);
    __shared__ __align__(16) float s_r[128];
    __shared__ float s_red[32];

    // ---------------- Phase A: r = vec(C^T) ----------------
    // (visibility covered by Phase C's first barrier; s_r read only in Phase B)
    if (t < 64) {
        int i = t >> 3, j = t & 7;
        s_r[2 * t]     = Cre[bs * 64 + j * 8 + i];
        s_r[2 * t + 1] = Cim[bs * 64 + j * 8 + i];
    }

    // ---------------- MFMA tile ownership ----------------
    const int tau0 = 2 * wv, tau1 = 2 * wv + 1;
    const int I0 = tau0 >> 2, J0 = tau0 & 3;
    const int I1 = tau1 >> 2, J1 = tau1 & 3;

    // per-thread redundant scalars (bit-identical across threads)
    float Elog = 0.f, gamma = 0.f;

    auto epilogue = [&](f32x4 P0, f32x4 Qa0, f32x4 P1, f32x4 Qa1, bool first, bool last) {
        #pragma unroll
        for (int r = 0; r < 4; ++r) {
            Q1[(I0 * 16 + qd * 4 + r) * PQ + J0 * 16 + c16] = Qa0[r];
            Q1[(I1 * 16 + qd * 4 + r) * PQ + J1 * 16 + c16] = Qa1[r];
        }
        float dv = 0.f;
        if (I0 == J0) {
            #pragma unroll
            for (int r = 0; r < 4; ++r) if (qd * 4 + r == c16) dv = fmaxf(dv, fabsf(P0[r]));
        }
        if (I1 == J1) {
            #pragma unroll
            for (int r = 0; r < 4; ++r) if (qd * 4 + r == c16) dv = fmaxf(dv, fabsf(P1[r]));
        }
        for (int off = 32; off; off >>= 1) dv = fmaxf(dv, __shfl_down(dv, off, 64));
        if (ln == 0) s_red[wv] = dv;
        __syncthreads();                         // covers Q1 writes + s_red
        float m = s_red[0];
        #pragma unroll
        for (int k = 1; k < 8; ++k) m = fmaxf(m, s_red[k]);
        Elog = first ? log2f(m) : 2.f * Elog + log2f(m);
        float ic = 1.f / m;
        float ci0[4], ci1[4];
        #pragma unroll
        for (int r = 0; r < 4; ++r) {
            ci0[r] = Qa0[r] - Q1[(J0 * 16 + c16) * PQ + I0 * 16 + qd * 4 + r];
            ci1[r] = Qa1[r] - Q1[(J1 * 16 + c16) * PQ + I1 * 16 + qd * 4 + r];
        }
        if (!last) {
            #pragma unroll
            for (int r = 0; r < 4; ++r) {
                ShRe[(I0 * 16 + qd * 4 + r) * PH + J0 * 16 + c16] = (_Float16)(P0[r] * ic);
                ShIm[(I0 * 16 + qd * 4 + r) * PH + J0 * 16 + c16] = (_Float16)(ci0[r] * ic);
                ShRe[(I1 * 16 + qd * 4 + r) * PH + J1 * 16 + c16] = (_Float16)(P1[r] * ic);
                ShIm[(I1 * 16 + qd * 4 + r) * PH + J1 * 16 + c16] = (_Float16)(ci1[r] * ic);
            }
            __syncthreads();
        } else {
            float fr = 0.f;
            #pragma unroll
            for (int r = 0; r < 4; ++r)
                fr += P0[r] * P0[r] + ci0[r] * ci0[r] + P1[r] * P1[r] + ci1[r] * ci1[r];
            fr *= ic * ic;
            for (int off = 32; off; off >>= 1) fr += __shfl_down(fr, off, 64);
            if (ln == 0) s_red[8 + wv] = fr;     // disjoint from s_red[0..8) read above
            __syncthreads();
            float fsum = 0.f;
            #pragma unroll
            for (int k = 0; k < 8; ++k) fsum += s_red[8 + k];
            gamma = exp2f(-(2.f * Elog + log2f(fsum)) * INV_P);
            // no guard barrier: Phase B uses disjoint s_red[16..32)
        }
    };

    // ---------------- Phase C: Gram via MFMA (single-buffer, 2 barriers/chunk) ----------
    h2 du_re[32], du_im[32];   // g-pairs of row ln, g in [64wv, 64wv+64)
    f32x4 gP0 = {0.f, 0.f, 0.f, 0.f}, gQ0 = {0.f, 0.f, 0.f, 0.f};
    f32x4 gP1 = {0.f, 0.f, 0.f, 0.f}, gQ1 = {0.f, 0.f, 0.f, 0.f};
    {
        const int srow = t >> 4;          // 0..31
        const int scb  = (t & 15) * 4;    // col base in chunk
        float4 pr0, pi0, pr1, pi1;
        pr0 = *(const float4*)&dre[srow * 512 + scb];
        pi0 = *(const float4*)&dim[srow * 512 + scb];
        pr1 = *(const float4*)&dre[(srow + 32) * 512 + scb];
        pi1 = *(const float4*)&dim[(srow + 32) * 512 + scb];
        for (int ch = 0; ch < 8; ++ch) {
            *(h2*)&ShRe[srow * PH + scb]     = h2{(_Float16)pr0.x, (_Float16)pr0.y};
            *(h2*)&ShRe[srow * PH + scb + 2] = h2{(_Float16)pr0.z, (_Float16)pr0.w};
            *(h2*)&ShIm[srow * PH + scb]     = h2{(_Float16)pi0.x, (_Float16)pi0.y};
            *(h2*)&ShIm[srow * PH + scb + 2] = h2{(_Float16)pi0.z, (_Float16)pi0.w};
            *(h2*)&ShRe[(srow + 32) * PH + scb]     = h2{(_Float16)pr1.x, (_Float16)pr1.y};
            *(h2*)&ShRe[(srow + 32) * PH + scb + 2] = h2{(_Float16)pr1.z, (_Float16)pr1.w};
            *(h2*)&ShIm[(srow + 32) * PH + scb]     = h2{(_Float16)pi1.x, (_Float16)pi1.y};
            *(h2*)&ShIm[(srow + 32) * PH + scb + 2] = h2{(_Float16)pi1.z, (_Float16)pi1.w};
            if (ch < 7) {   // register prefetch: no LDS/store in flight -> no barrier drain
                int gc = (ch + 1) * 64;
                pr0 = *(const float4*)&dre[srow * 512 + gc + scb];
                pi0 = *(const float4*)&dim[srow * 512 + gc + scb];
                pr1 = *(const float4*)&dre[(srow + 32) * 512 + gc + scb];
                pi1 = *(const float4*)&dim[(srow + 32) * 512 + gc + scb];
            }
            __syncthreads();
            #pragma unroll
            for (int ks = 0; ks < 64; ks += 32) {
                f16x8 arI0 = *(const f16x8*)&ShRe[(I0 * 16 + c16) * PH + ks + qd * 8];
                f16x8 aiI0 = *(const f16x8*)&ShIm[(I0 * 16 + c16) * PH + ks + qd * 8];
                f16x8 arJ0 = *(const f16x8*)&ShRe[(J0 * 16 + c16) * PH + ks + qd * 8];
                f16x8 aiJ0 = *(const f16x8*)&ShIm[(J0 * 16 + c16) * PH + ks + qd * 8];
                gP0 = __builtin_amdgcn_mfma_f32_16x16x32_f16(arI0, arJ0, gP0, 0, 0, 0);
                gP0 = __builtin_amdgcn_mfma_f32_16x16x32_f16(aiI0, aiJ0, gP0, 0, 0, 0);
                gQ0 = __builtin_amdgcn_mfma_f32_16x16x32_f16(aiI0, arJ0, gQ0, 0, 0, 0);
                f16x8 arI1 = *(const f16x8*)&ShRe[(I1 * 16 + c16) * PH + ks + qd * 8];
                f16x8 aiI1 = *(const f16x8*)&ShIm[(I1 * 16 + c16) * PH + ks + qd * 8];
                f16x8 arJ1 = *(const f16x8*)&ShRe[(J1 * 16 + c16) * PH + ks + qd * 8];
                f16x8 aiJ1 = *(const f16x8*)&ShIm[(J1 * 16 + c16) * PH + ks + qd * 8];
                gP1 = __builtin_amdgcn_mfma_f32_16x16x32_f16(arI1, arJ1, gP1, 0, 0, 0);
                gP1 = __builtin_amdgcn_mfma_f32_16x16x32_f16(aiI1, aiJ1, gP1, 0, 0, 0);
                gQ1 = __builtin_amdgcn_mfma_f32_16x16x32_f16(aiI1, arJ1, gQ1, 0, 0, 0);
            }
            if (ch == wv) {
                #pragma unroll
                for (int c = 0; c < 8; ++c) {
                    uint4 aw = *(const uint4*)&ShRe[ln * PH + 8 * c];
                    du_re[4 * c + 0] = bch2(aw.x); du_re[4 * c + 1] = bch2(aw.y);
                    du_re[4 * c + 2] = bch2(aw.z); du_re[4 * c + 3] = bch2(aw.w);
                    uint4 bw = *(const uint4*)&ShIm[ln * PH + 8 * c];
                    du_im[4 * c + 0] = bch2(bw.x); du_im[4 * c + 1] = bch2(bw.y);
                    du_im[4 * c + 2] = bch2(bw.z); du_im[4 * c + 3] = bch2(bw.w);
                }
            }
            __syncthreads();
        }
    }
    epilogue(gP0, gQ0, gP1, gQ1, true, false);

    // ---------------- Phase D: 7 scaled squarings via MFMA ----------------
    for (int sq = 0; sq < N_SQ; ++sq) {
        f32x4 P0 = {0.f, 0.f, 0.f, 0.f}, Qa0 = {0.f, 0.f, 0.f, 0.f};
        f32x4 P1 = {0.f, 0.f, 0.f, 0.f}, Qa1 = {0.f, 0.f, 0.f, 0.f};
        #pragma unroll
        for (int ks = 0; ks < 64; ks += 32) {
            f16x8 arI0 = *(const f16x8*)&ShRe[(I0 * 16 + c16) * PH + ks + qd * 8];
            f16x8 aiI0 = *(const f16x8*)&ShIm[(I0 * 16 + c16) * PH + ks + qd * 8];
            f16x8 arJ0 = *(const f16x8*)&ShRe[(J0 * 16 + c16) * PH + ks + qd * 8];
            f16x8 aiJ0 = *(const f16x8*)&ShIm[(J0 * 16 + c16) * PH + ks + qd * 8];
            P0  = __builtin_amdgcn_mfma_f32_16x16x32_f16(arI0, arJ0, P0, 0, 0, 0);
            P0  = __builtin_amdgcn_mfma_f32_16x16x32_f16(aiI0, aiJ0, P0, 0, 0, 0);
            Qa0 = __builtin_amdgcn_mfma_f32_16x16x32_f16(aiI0, arJ0, Qa0, 0, 0, 0);
            f16x8 arI1 = *(const f16x8*)&ShRe[(I1 * 16 + c16) * PH + ks + qd * 8];
            f16x8 aiI1 = *(const f16x8*)&ShIm[(I1 * 16 + c16) * PH + ks + qd * 8];
            f16x8 arJ1 = *(const f16x8*)&ShRe[(J1 * 16 + c16) * PH + ks + qd * 8];
            f16x8 aiJ1 = *(const f16x8*)&ShIm[(J1 * 16 + c16) * PH + ks + qd * 8];
            P1  = __builtin_amdgcn_mfma_f32_16x16x32_f16(arI1, arJ1, P1, 0, 0, 0);
            P1  = __builtin_amdgcn_mfma_f32_16x16x32_f16(aiI1, aiJ1, P1, 0, 0, 0);
            Qa1 = __builtin_amdgcn_mfma_f32_16x16x32_f16(aiI1, arJ1, Qa1, 0, 0, 0);
        }
        epilogue(P0, Qa0, P1, Qa1, false, sq == N_SQ - 1);
    }

    // ---------------- Phase B (after D): Dhr[g] + dV column tile; L2-warm loads ----------
    float dhr_re, dhr_im, res_g, theta;
    h2 dV[64];    // D[m][t] packed (re,im) f16
    {
        float dr0 = 0.f, dr1 = 0.f, di0 = 0.f, di1 = 0.f;
        #pragma unroll
        for (int m = 0; m < 64; ++m) {
            float ar = dre[m * 512 + t], ai = dim[m * 512 + t];
            dV[m] = h2{(_Float16)ar, (_Float16)ai};
            float rr = s_r[2 * m], ri = s_r[2 * m + 1];
            if (m & 1) { dr1 += ar * rr + ai * ri; di1 += ar * ri - ai * rr; }
            else       { dr0 += ar * rr + ai * ri; di0 += ar * ri - ai * rr; }
        }
        dhr_re = dr0 + dr1; dhr_im = di0 + di1;
        float sv = dhr_re * dhr_re;
        float mv = sqrtf(dhr_re * dhr_re + dhr_im * dhr_im);
        for (int off = 32; off; off >>= 1) {
            sv += __shfl_down(sv, off, 64);
            mv = fmaxf(mv, __shfl_down(mv, off, 64));
        }
        if (ln == 0) { s_red[16 + wv] = sv; s_red[24 + wv] = mv; }   // disjoint slots
        __syncthreads();
        float ss = 0.f, mmx = 0.f;
        #pragma unroll
        for (int k = 0; k < 8; ++k) { ss += s_red[16 + k]; mmx = fmaxf(mmx, s_red[24 + k]); }
        res_g = dhr_re / (sqrtf(ss) + EPS_F);
        theta = 0.5f * mmx * gamma;
    }

    // ---------------- Phase E: 16 ISTA layers, 1 barrier/layer, no global stores --------
    const int resh_base = 64 * wv;
    float* const sHuMe = uBuf + 2304 + wv * 128;   // wave-private hu copy

    for (int l = 0; l < 16; ++l) {
        sResH[t] = (_Float16)res_g;          // wave-private range, read by own wave only
        float uA = 0.f, uB = 0.f, vA = 0.f, vB = 0.f;
        #pragma unroll
        for (int c = 0; c < 8; ++c) {
            uint4 rw = *(const uint4*)&sResH[resh_base + 8 * c];
            h2 r0 = bch2(rw.x), r1 = bch2(rw.y), r2 = bch2(rw.z), r3 = bch2(rw.w);
            uA = cdot2(du_re[4 * c + 0], r0, uA);  vA = cdot2(du_im[4 * c + 0], r0, vA);
            uB = cdot2(du_re[4 * c + 1], r1, uB);  vB = cdot2(du_im[4 * c + 1], r1, vB);
            uA = cdot2(du_re[4 * c + 2], r2, uA);  vA = cdot2(du_im[4 * c + 2], r2, vA);
            uB = cdot2(du_re[4 * c + 3], r3, uB);  vB = cdot2(du_im[4 * c + 3], r3, vB);
        }
        float* sUpL = uBuf + (l & 1) * 1024;   // ping-pong partial buffer
        *(float2*)&sUpL[t * 2] = make_float2(uA + uB, vA + vB);
        __syncthreads();                       // the only barrier this layer (LDS-only drain)
        // every wave redundantly reduces (bit-identical across waves)
        float uR = 0.f, uI = 0.f;
        #pragma unroll
        for (int w8 = 0; w8 < 8; ++w8) {
            float2 p = *(const float2*)&sUpL[(w8 * 64 + ln) * 2];
            uR += p.x; uI += p.y;
        }
        h2 hu1 = h2{(_Float16)uR, (_Float16)uI};
        h2 hu2 = h2{(_Float16)uI, (_Float16)(-uR)};
        *(float2*)&sHuMe[2 * ln] = make_float2(bcf(hu1), bcf(hu2));
        // in-wave readback of own sHu copy (ds in-order, no barrier)
        float wRa = 0.f, wRb = 0.f, wIa = 0.f, wIb = 0.f;
        #pragma unroll
        for (int mm = 0; mm < 32; ++mm) {
            float4 hq = *(const float4*)&sHuMe[4 * mm];
            wRa = cdot2(dV[2 * mm],     bch2f(hq.x), wRa);
            wIa = cdot2(dV[2 * mm],     bch2f(hq.y), wIa);
            wRb = cdot2(dV[2 * mm + 1], bch2f(hq.z), wRb);
            wIb = cdot2(dV[2 * mm + 1], bch2f(hq.w), wIb);
        }
        float sre = res_g + gamma * (dhr_re - (wRa + wRb));
        float sim = gamma * (dhr_im - (wIa + wIb));
        float mag = sqrtf(sre * sre + sim * sim);
        res_g = fmaxf(mag - theta, 0.f);
        resHist[l * 512 + t] = res_g;          // LDS, own slot, no drain at next barrier
    }

    // ---------------- Phase F: per-(b,s) minmax + raw store ----------------
    {
        float mn = res_g, mx = res_g;
        for (int off = 32; off; off >>= 1) {
            mn = fminf(mn, __shfl_down(mn, off, 64));
            mx = fmaxf(mx, __shfl_down(mx, off, 64));
        }
        if (ln == 0) { s_red[wv] = mn; s_red[8 + wv] = mx; }
        __syncthreads();
        float lo = s_red[0], hi = s_red[8];
        #pragma unroll
        for (int k = 1; k < 8; ++k) { lo = fminf(lo, s_red[k]); hi = fmaxf(hi, s_red[8 + k]); }
        out[bs * 512 + t] = (res_g - lo) / (hi - lo + EPS_F);
        ws[bs * 512 + t] = res_g;
    }

    // ---------------- bulk out_init store (deferred from Phase E) ----------------
    {
        float* out_init = out + 40960 + (size_t)bs * 8192;
        #pragma unroll
        for (int l = 0; l < 16; ++l)
            out_init[l * 512 + t] = resHist[l * 512 + t];   // own slot, no barrier needed
    }
}

__global__ __launch_bounds__(512) void ista_ave_kernel(
    const float* __restrict__ ws, float* __restrict__ out)
{
    const int b = blockIdx.x;    // 0..7
    const int g = threadIdx.x;   // 0..511
    __shared__ float s_red[16];
    float acc = 0.f;
    #pragma unroll
    for (int s = 0; s < 9; ++s) acc += ws[(b * 9 + s) * 512 + g];
    acc *= (1.f / 9.f);
    float mn = acc, mx = acc;
    for (int off = 32; off; off >>= 1) {
        mn = fminf(mn, __shfl_down(mn, off, 64));
        mx = fmaxf(mx, __shfl_down(mx, off, 64));
    }
    if ((g & 63) == 0) { s_red[g >> 6] = mn; s_red[8 + (g >> 6)] = mx; }
    __syncthreads();
    float lo = s_red[0], hi = s_red[8];
    #pragma unroll
    for (int k = 1; k < 8; ++k) { lo = fminf(lo, s_red[k]); hi = fmaxf(hi, s_red[8 + k]); }
    out[36864 + b * 512 + g] = (acc - lo) / (hi - lo + EPS_F);
}

extern "C" void kernel_launch(void* const* d_in, const int* in_sizes, int n_in,
                              void* d_out, int out_size, void* d_ws, size_t ws_size,
                              hipStream_t stream) {
    const float* Dre = (const float*)d_in[0];
    const float* Dim = (const float*)d_in[1];
    const float* Cre = (const float*)d_in[2];
    const float* Cim = (const float*)d_in[3];
    float* out = (float*)d_out;
    float* ws  = (float*)d_ws;

    ista_main_kernel<<<72, 512, 0, stream>>>(Dre, Dim, Cre, Cim, out, ws);
    ista_ave_kernel<<<8, 512, 0, stream>>>(ws, out);
}